// Round 2
// baseline (3809.337 us; speedup 1.0000x reference)
//
#include <hip/hip_runtime.h>

#define NGENE 1000
#define HID   64

// ---------------- degree accumulation ----------------
__global__ void k_degrees(const int* __restrict__ src, const int* __restrict__ dst,
                          float* __restrict__ dout, float* __restrict__ din, int ne) {
  int t = blockIdx.x * blockDim.x + threadIdx.x;
  if (t < ne) {
    atomicAdd(&dout[src[t]], 1.0f);
    atomicAdd(&din[dst[t]], 1.0f);
  }
}

// in-place: deg -> rsqrt(max(deg,1))
__global__ void k_norms(float* __restrict__ buf, int n2) {
  int t = blockIdx.x * blockDim.x + threadIdx.x;
  if (t < n2) {
    float v = buf[t];
    buf[t] = rsqrtf(v < 1.0f ? 1.0f : v);
  }
}

// ---------------- GEMM0: t0 = (concat(xu,xs) @ W0) * nsrc ----------------
// C tile: 64 nodes x 64 cols per block, 4x4 per thread, KT=16, K=2000 (125 tiles)
__global__ __launch_bounds__(256) void k_gemm0(
    const float* __restrict__ xu, const float* __restrict__ xs,
    const float* __restrict__ W0, const float* __restrict__ nsrc,
    float* __restrict__ t0, int n) {
  __shared__ __align__(16) float As[16][68];  // [kk][node], pad 68 keeps rows 16B-aligned
  __shared__ __align__(16) float Bs[16][64];  // [kk][col]
  const int t  = threadIdx.x;
  const int bi = blockIdx.x * 64;
  const int tx = t & 15;   // col group -> cols tx*4..+3
  const int ty = t >> 4;   // node group -> nodes ty*4..+3
  float acc[4][4] = {};

  for (int k0 = 0; k0 < 2 * NGENE; k0 += 16) {
    // stage A: 64 nodes x 16 k
#pragma unroll
    for (int r = 0; r < 4; ++r) {
      int idx  = r * 256 + t;
      int node = idx >> 4, kk = idx & 15;
      int row  = bi + node, k = k0 + kk;
      float v = 0.0f;
      if (row < n) v = (k < NGENE) ? xu[row * NGENE + k] : xs[row * NGENE + (k - NGENE)];
      As[kk][node] = v;
    }
    // stage B: 16 k x 64 cols
#pragma unroll
    for (int r = 0; r < 4; ++r) {
      int idx = r * 256 + t;
      int kk  = idx >> 6, j = idx & 63;
      Bs[kk][j] = W0[(k0 + kk) * HID + j];
    }
    __syncthreads();
#pragma unroll
    for (int kk = 0; kk < 16; ++kk) {
      float4 a4 = *(const float4*)&As[kk][ty * 4];
      float4 b4 = *(const float4*)&Bs[kk][tx * 4];
      float av[4] = {a4.x, a4.y, a4.z, a4.w};
      float bv[4] = {b4.x, b4.y, b4.z, b4.w};
#pragma unroll
      for (int i = 0; i < 4; ++i)
#pragma unroll
        for (int j = 0; j < 4; ++j)
          acc[i][j] = fmaf(av[i], bv[j], acc[i][j]);
    }
    __syncthreads();
  }

#pragma unroll
  for (int nn = 0; nn < 4; ++nn) {
    int node = bi + ty * 4 + nn;
    if (node < n) {
      float s = nsrc[node];
      float4 o;
      o.x = acc[nn][0] * s; o.y = acc[nn][1] * s;
      o.z = acc[nn][2] * s; o.w = acc[nn][3] * s;
      *(float4*)&t0[node * HID + tx * 4] = o;
    }
  }
}

// ---------------- edge scatter: agg[dst] += feat[src], 16 lanes/edge ----------------
__global__ void k_scatter(const float* __restrict__ feat, const int* __restrict__ src,
                          const int* __restrict__ dst, float* __restrict__ agg, int ne) {
  int t = blockIdx.x * blockDim.x + threadIdx.x;
  int e = t >> 4, q = t & 15;
  if (e < ne) {
    int s = src[e], d = dst[e];
    float4 v = *(const float4*)&feat[s * HID + q * 4];
    float* p = &agg[d * HID + q * 4];
    atomicAdd(p + 0, v.x);
    atomicAdd(p + 1, v.y);
    atomicAdd(p + 2, v.z);
    atomicAdd(p + 3, v.w);
  }
}

// ---------------- layer-0 finish + layer-1 pre-scale ----------------
// h1s = relu(agg0 * ndst + b0) * nsrc
__global__ void k_act(const float* __restrict__ agg, const float* __restrict__ ndst,
                      const float* __restrict__ nsrc, const float* __restrict__ b0,
                      float* __restrict__ h1s, int n) {
  int t = blockIdx.x * blockDim.x + threadIdx.x;
  if (t < n * 16) {
    int node = t >> 4, q = t & 15;
    float4 a = *(const float4*)&agg[node * HID + q * 4];
    float4 b = *(const float4*)&b0[q * 4];
    float nd = ndst[node], ns = nsrc[node];
    float4 h;
    h.x = fmaxf(fmaf(a.x, nd, b.x), 0.0f) * ns;
    h.y = fmaxf(fmaf(a.y, nd, b.y), 0.0f) * ns;
    h.z = fmaxf(fmaf(a.z, nd, b.z), 0.0f) * ns;
    h.w = fmaxf(fmaf(a.w, nd, b.w), 0.0f) * ns;
    *(float4*)&h1s[node * HID + q * 4] = h;
  }
}

// ---------------- fused GEMM1 + bias + output ----------------
// out[i,g] = (A2[i,:]·W1[:,g] + b1[g]) * xu[i,g] + (A2[i,:]·W1[:,1000+g] + b1[1000+g]) * xs[i,g]
// A2 = agg1 * ndst.  Tile: 64 nodes x 64 genes per block, 4x4 per thread, K=64.
__global__ __launch_bounds__(256) void k_final(
    const float* __restrict__ agg, const float* __restrict__ ndst,
    const float* __restrict__ W1, const float* __restrict__ b1,
    const float* __restrict__ xu, const float* __restrict__ xs,
    float* __restrict__ out, int n) {
  __shared__ __align__(16) float A2s[64][68];  // [j][node]
  __shared__ __align__(16) float Wb[64][64];   // [j][gene]  (beta half)
  __shared__ __align__(16) float Wg[64][64];   // [j][gene]  (gamma half)
  const int t  = threadIdx.x;
  const int bi = blockIdx.x * 64;
  const int g0 = blockIdx.y * 64;
  const int tg = t & 15;   // genes tg*4..+3
  const int tn = t >> 4;   // nodes tn*4..+3

#pragma unroll
  for (int r = 0; r < 16; ++r) {
    int idx = r * 256 + t;
    // A staging: a_node = idx>>6, aj = idx&63
    int a_node = idx >> 6, aj = idx & 63;
    int row = bi + a_node;
    float v = 0.0f;
    if (row < n) v = agg[row * HID + aj] * ndst[row];
    A2s[aj][a_node] = v;
    // W staging: wj = idx>>6 (k index), g = idx&63 (gene index)  -- FIXED
    int wj = idx >> 6, g = idx & 63;
    int gg = g0 + g;
    float wb = 0.0f, wg = 0.0f;
    if (gg < NGENE) {
      wb = W1[wj * (2 * NGENE) + gg];
      wg = W1[wj * (2 * NGENE) + NGENE + gg];
    }
    Wb[wj][g] = wb;
    Wg[wj][g] = wg;
  }
  __syncthreads();

  float ab[4][4] = {}, ag[4][4] = {};
#pragma unroll 4
  for (int j = 0; j < 64; ++j) {
    float4 a4 = *(const float4*)&A2s[j][tn * 4];
    float4 b4 = *(const float4*)&Wb[j][tg * 4];
    float4 g4 = *(const float4*)&Wg[j][tg * 4];
    float av[4] = {a4.x, a4.y, a4.z, a4.w};
    float bv[4] = {b4.x, b4.y, b4.z, b4.w};
    float gv[4] = {g4.x, g4.y, g4.z, g4.w};
#pragma unroll
    for (int i = 0; i < 4; ++i)
#pragma unroll
      for (int c = 0; c < 4; ++c) {
        ab[i][c] = fmaf(av[i], bv[c], ab[i][c]);
        ag[i][c] = fmaf(av[i], gv[c], ag[i][c]);
      }
  }

  int gene = g0 + tg * 4;
  if (gene < NGENE) {
    float4 bb = *(const float4*)&b1[gene];
    float4 bg = *(const float4*)&b1[NGENE + gene];
#pragma unroll
    for (int nn = 0; nn < 4; ++nn) {
      int node = bi + tn * 4 + nn;
      if (node < n) {
        float4 u = *(const float4*)&xu[node * NGENE + gene];
        float4 s = *(const float4*)&xs[node * NGENE + gene];
        float4 o;
        o.x = (ab[nn][0] + bb.x) * u.x + (ag[nn][0] + bg.x) * s.x;
        o.y = (ab[nn][1] + bb.y) * u.y + (ag[nn][1] + bg.y) * s.y;
        o.z = (ab[nn][2] + bb.z) * u.z + (ag[nn][2] + bg.z) * s.z;
        o.w = (ab[nn][3] + bb.w) * u.w + (ag[nn][3] + bg.w) * s.w;
        *(float4*)&out[node * NGENE + gene] = o;
      }
    }
  }
}

extern "C" void kernel_launch(void* const* d_in, const int* in_sizes, int n_in,
                              void* d_out, int out_size, void* d_ws, size_t ws_size,
                              hipStream_t stream) {
  const float* xu = (const float*)d_in[0];
  const float* xs = (const float*)d_in[1];
  const float* W0 = (const float*)d_in[2];
  const float* b0 = (const float*)d_in[3];
  const float* W1 = (const float*)d_in[4];
  const float* b1 = (const float*)d_in[5];
  const int* src  = (const int*)d_in[6];
  const int* dst  = (const int*)d_in[7];
  float* out = (float*)d_out;

  const int n  = in_sizes[0] / NGENE;  // 50000
  const int ne = in_sizes[6];          // 1600000

  float* ws   = (float*)d_ws;
  float* nsrc = ws;                 // n
  float* ndst = ws + n;             // n
  float* t0   = ws + 2 * n;         // n*64 (t0, then reused as h1s)
  float* agg  = ws + 2 * n + HID * n;  // n*64 (agg0, then agg1)

  // degrees -> norms
  hipMemsetAsync(ws, 0, (size_t)(2 * n) * sizeof(float), stream);
  hipMemsetAsync(agg, 0, (size_t)(HID * n) * sizeof(float), stream);
  k_degrees<<<(ne + 255) / 256, 256, 0, stream>>>(src, dst, nsrc, ndst, ne);
  k_norms<<<(2 * n + 255) / 256, 256, 0, stream>>>(ws, 2 * n);

  // layer 0
  k_gemm0<<<(n + 63) / 64, 256, 0, stream>>>(xu, xs, W0, nsrc, t0, n);
  k_scatter<<<(ne * 16 + 255) / 256, 256, 0, stream>>>(t0, src, dst, agg, ne);
  k_act<<<(n * 16 + 255) / 256, 256, 0, stream>>>(agg, ndst, nsrc, b0, t0, n);

  // layer 1
  hipMemsetAsync(agg, 0, (size_t)(HID * n) * sizeof(float), stream);
  k_scatter<<<(ne * 16 + 255) / 256, 256, 0, stream>>>(t0, src, dst, agg, ne);

  // fused GEMM1 + bias + beta*xu + gamma*xs
  dim3 fg((n + 63) / 64, (NGENE + 63) / 64);
  k_final<<<fg, 256, 0, stream>>>(agg, ndst, W1, b1, xu, xs, out, n);
}

// Round 3
// 1536.221 us; speedup vs baseline: 2.4797x; 2.4797x over previous
//
#include <hip/hip_runtime.h>

#define NGENE 1000
#define HID   64

// ---------------- int degree histograms (src & dst) ----------------
__global__ void k_hist(const int* __restrict__ src, const int* __restrict__ dst,
                       int* __restrict__ hsrc, int* __restrict__ hdst, int ne) {
  int t = blockIdx.x * blockDim.x + threadIdx.x;
  if (t < ne) {
    atomicAdd(&hsrc[src[t]], 1);
    atomicAdd(&hdst[dst[t]], 1);
  }
}

// nsrc[i] = rsqrt(max(deg_out,1))
__global__ void k_norms(const int* __restrict__ hsrc, float* __restrict__ nsrc, int n) {
  int t = blockIdx.x * blockDim.x + threadIdx.x;
  if (t < n) {
    float v = (float)hsrc[t];
    nsrc[t] = rsqrtf(v < 1.0f ? 1.0f : v);
  }
}

// ---------------- single-block exclusive scan of hdst -> row_ptr, cursor ----------------
__global__ __launch_bounds__(256) void k_scan(const int* __restrict__ hist,
                                              int* __restrict__ row_ptr,
                                              int* __restrict__ cursor, int n) {
  __shared__ int sums[256];
  const int t = threadIdx.x;
  const int per = (n + 255) / 256;
  const int lo = t * per;
  const int hi = (lo + per < n) ? lo + per : n;
  int s = 0;
  for (int i = lo; i < hi; ++i) s += hist[i];
  sums[t] = s;
  __syncthreads();
  // Hillis-Steele inclusive scan over 256 partial sums
  for (int off = 1; off < 256; off <<= 1) {
    int v = sums[t];
    int u = (t >= off) ? sums[t - off] : 0;
    __syncthreads();
    sums[t] = v + u;
    __syncthreads();
  }
  int base = (t == 0) ? 0 : sums[t - 1];
  for (int i = lo; i < hi; ++i) {
    row_ptr[i] = base;
    cursor[i]  = base;
    base += hist[i];
  }
  if (t == 255) row_ptr[n] = base;
}

// ---------------- fill: edge srcs sorted by dst ----------------
__global__ void k_fill(const int* __restrict__ src, const int* __restrict__ dst,
                       int* __restrict__ cursor, int* __restrict__ esrc, int ne) {
  int t = blockIdx.x * blockDim.x + threadIdx.x;
  if (t < ne) {
    int pos = atomicAdd(&cursor[dst[t]], 1);
    esrc[pos] = src[t];
  }
}

// ---------------- GEMM0: t0 = (concat(xu,xs) @ W0) * nsrc ----------------
__global__ __launch_bounds__(256) void k_gemm0(
    const float* __restrict__ xu, const float* __restrict__ xs,
    const float* __restrict__ W0, const float* __restrict__ nsrc,
    float* __restrict__ t0, int n) {
  __shared__ __align__(16) float As[16][68];
  __shared__ __align__(16) float Bs[16][64];
  const int t  = threadIdx.x;
  const int bi = blockIdx.x * 64;
  const int tx = t & 15;
  const int ty = t >> 4;
  float acc[4][4] = {};

  for (int k0 = 0; k0 < 2 * NGENE; k0 += 16) {
#pragma unroll
    for (int r = 0; r < 4; ++r) {
      int idx  = r * 256 + t;
      int node = idx >> 4, kk = idx & 15;
      int row  = bi + node, k = k0 + kk;
      float v = 0.0f;
      if (row < n) v = (k < NGENE) ? xu[row * NGENE + k] : xs[row * NGENE + (k - NGENE)];
      As[kk][node] = v;
    }
#pragma unroll
    for (int r = 0; r < 4; ++r) {
      int idx = r * 256 + t;
      int kk  = idx >> 6, j = idx & 63;
      Bs[kk][j] = W0[(k0 + kk) * HID + j];
    }
    __syncthreads();
#pragma unroll
    for (int kk = 0; kk < 16; ++kk) {
      float4 a4 = *(const float4*)&As[kk][ty * 4];
      float4 b4 = *(const float4*)&Bs[kk][tx * 4];
      float av[4] = {a4.x, a4.y, a4.z, a4.w};
      float bv[4] = {b4.x, b4.y, b4.z, b4.w};
#pragma unroll
      for (int i = 0; i < 4; ++i)
#pragma unroll
        for (int j = 0; j < 4; ++j)
          acc[i][j] = fmaf(av[i], bv[j], acc[i][j]);
    }
    __syncthreads();
  }

#pragma unroll
  for (int nn = 0; nn < 4; ++nn) {
    int node = bi + ty * 4 + nn;
    if (node < n) {
      float s = nsrc[node];
      float4 o;
      o.x = acc[nn][0] * s; o.y = acc[nn][1] * s;
      o.z = acc[nn][2] * s; o.w = acc[nn][3] * s;
      *(float4*)&t0[node * HID + tx * 4] = o;
    }
  }
}

// ---------------- CSR gather aggregation, one wave per dst node ----------------
// mode 0: h1s = relu(acc*ndst + b0)*nsrc     (layer-0 epilogue + layer-1 prescale)
// mode 1: A2  = acc*ndst                     (layer-1 pre-GEMM)
__global__ __launch_bounds__(256) void k_gather(
    const float* __restrict__ feat, const int* __restrict__ row_ptr,
    const int* __restrict__ esrc, const float* __restrict__ b0,
    const float* __restrict__ nsrc, float* __restrict__ outb, int n, int mode) {
  int wave = blockIdx.x * 4 + (threadIdx.x >> 6);
  int l = threadIdx.x & 63;
  if (wave >= n) return;
  int beg = row_ptr[wave], end = row_ptr[wave + 1];
  float acc = 0.0f;
  int e = beg;
  for (; e + 4 <= end; e += 4) {
    int s0 = esrc[e], s1 = esrc[e + 1], s2 = esrc[e + 2], s3 = esrc[e + 3];
    float f0 = feat[s0 * HID + l];
    float f1 = feat[s1 * HID + l];
    float f2 = feat[s2 * HID + l];
    float f3 = feat[s3 * HID + l];
    acc += (f0 + f1) + (f2 + f3);
  }
  for (; e < end; ++e) acc += feat[esrc[e] * HID + l];
  float deg = (float)(end - beg);
  float nd = rsqrtf(deg < 1.0f ? 1.0f : deg);
  if (mode == 0) {
    outb[wave * HID + l] = fmaxf(fmaf(acc, nd, b0[l]), 0.0f) * nsrc[wave];
  } else {
    outb[wave * HID + l] = acc * nd;
  }
}

// ---------------- fused GEMM1 + bias + output ----------------
// out[i,g] = (A2[i,:]·W1[:,g]+b1[g])*xu[i,g] + (A2[i,:]·W1[:,1000+g]+b1[1000+g])*xs[i,g]
__global__ __launch_bounds__(256) void k_final(
    const float* __restrict__ A2, const float* __restrict__ W1,
    const float* __restrict__ b1, const float* __restrict__ xu,
    const float* __restrict__ xs, float* __restrict__ out, int n) {
  __shared__ __align__(16) float A2s[64][68];
  __shared__ __align__(16) float Wb[64][64];
  __shared__ __align__(16) float Wg[64][64];
  const int t  = threadIdx.x;
  const int bi = blockIdx.x * 64;
  const int g0 = blockIdx.y * 64;
  const int tg = t & 15;
  const int tn = t >> 4;

#pragma unroll
  for (int r = 0; r < 16; ++r) {
    int idx = r * 256 + t;
    int a_node = idx >> 6, aj = idx & 63;
    int row = bi + a_node;
    float v = 0.0f;
    if (row < n) v = A2[row * HID + aj];
    A2s[aj][a_node] = v;
    int wj = idx >> 6, g = idx & 63;
    int gg = g0 + g;
    float wb = 0.0f, wg = 0.0f;
    if (gg < NGENE) {
      wb = W1[wj * (2 * NGENE) + gg];
      wg = W1[wj * (2 * NGENE) + NGENE + gg];
    }
    Wb[wj][g] = wb;
    Wg[wj][g] = wg;
  }
  __syncthreads();

  float ab[4][4] = {}, ag[4][4] = {};
#pragma unroll 4
  for (int j = 0; j < 64; ++j) {
    float4 a4 = *(const float4*)&A2s[j][tn * 4];
    float4 b4 = *(const float4*)&Wb[j][tg * 4];
    float4 g4 = *(const float4*)&Wg[j][tg * 4];
    float av[4] = {a4.x, a4.y, a4.z, a4.w};
    float bv[4] = {b4.x, b4.y, b4.z, b4.w};
    float gv[4] = {g4.x, g4.y, g4.z, g4.w};
#pragma unroll
    for (int i = 0; i < 4; ++i)
#pragma unroll
      for (int c = 0; c < 4; ++c) {
        ab[i][c] = fmaf(av[i], bv[c], ab[i][c]);
        ag[i][c] = fmaf(av[i], gv[c], ag[i][c]);
      }
  }

  int gene = g0 + tg * 4;
  if (gene < NGENE) {
    float4 bb = *(const float4*)&b1[gene];
    float4 bg = *(const float4*)&b1[NGENE + gene];
#pragma unroll
    for (int nn = 0; nn < 4; ++nn) {
      int node = bi + tn * 4 + nn;
      if (node < n) {
        float4 u = *(const float4*)&xu[node * NGENE + gene];
        float4 s = *(const float4*)&xs[node * NGENE + gene];
        float4 o;
        o.x = (ab[nn][0] + bb.x) * u.x + (ag[nn][0] + bg.x) * s.x;
        o.y = (ab[nn][1] + bb.y) * u.y + (ag[nn][1] + bg.y) * s.y;
        o.z = (ab[nn][2] + bb.z) * u.z + (ag[nn][2] + bg.z) * s.z;
        o.w = (ab[nn][3] + bb.w) * u.w + (ag[nn][3] + bg.w) * s.w;
        *(float4*)&out[node * NGENE + gene] = o;
      }
    }
  }
}

extern "C" void kernel_launch(void* const* d_in, const int* in_sizes, int n_in,
                              void* d_out, int out_size, void* d_ws, size_t ws_size,
                              hipStream_t stream) {
  const float* xu = (const float*)d_in[0];
  const float* xs = (const float*)d_in[1];
  const float* W0 = (const float*)d_in[2];
  const float* b0 = (const float*)d_in[3];
  const float* W1 = (const float*)d_in[4];
  const float* b1 = (const float*)d_in[5];
  const int* src  = (const int*)d_in[6];
  const int* dst  = (const int*)d_in[7];
  float* out = (float*)d_out;

  const int n  = in_sizes[0] / NGENE;  // 50000
  const int ne = in_sizes[6];          // 1600000

  // workspace layout
  float* fws  = (float*)d_ws;
  float* nsrc = fws;                   // n floats
  float* t0   = fws + n;               // 64n floats (gemm0 out; later reused as A2)
  float* h1s  = fws + n + HID * n;     // 64n floats
  int* iws     = (int*)(fws + n + 2 * HID * n);
  int* hsrc    = iws;                  // n
  int* hdst    = iws + n;              // n
  int* row_ptr = iws + 2 * n;          // n+1
  int* cursor  = iws + 3 * n + 1;      // n
  int* esrc    = iws + 4 * n + 1;      // ne
  float* A2 = t0;                      // alias: t0 dead once h1s built

  // CSR build + norms
  hipMemsetAsync(hsrc, 0, (size_t)(2 * n) * sizeof(int), stream);
  k_hist<<<(ne + 255) / 256, 256, 0, stream>>>(src, dst, hsrc, hdst, ne);
  k_norms<<<(n + 255) / 256, 256, 0, stream>>>(hsrc, nsrc, n);
  k_scan<<<1, 256, 0, stream>>>(hdst, row_ptr, cursor, n);
  k_fill<<<(ne + 255) / 256, 256, 0, stream>>>(src, dst, cursor, esrc, ne);

  // layer 0
  k_gemm0<<<(n + 63) / 64, 256, 0, stream>>>(xu, xs, W0, nsrc, t0, n);
  k_gather<<<(n + 3) / 4, 256, 0, stream>>>(t0, row_ptr, esrc, b0, nsrc, h1s, n, 0);

  // layer 1 aggregation (A2 = agg1 * ndst), A2 aliases t0
  k_gather<<<(n + 3) / 4, 256, 0, stream>>>(h1s, row_ptr, esrc, b0, nsrc, A2, n, 1);

  // fused GEMM1 + bias + beta*xu + gamma*xs
  dim3 fg((n + 63) / 64, (NGENE + 63) / 64);
  k_final<<<fg, 256, 0, stream>>>(A2, W1, b1, xu, xs, out, n);
}